// Round 11
// baseline (203.058 us; speedup 1.0000x reference)
//
#include <hip/hip_runtime.h>

#define NSAMP 4096
#define NITER 200

// DPP fmac/mul: src0 (resid register) read through row_ror:t.
#define DPL(op, acc, rr, mm, rot) \
  op " " acc ", " rr ", " mm " row_ror:" #rot " row_mask:0xf bank_mask:0xf\n\t"

// ---------------------------------------------------------------------------
// R11: fused kernel, d=32 loop (R9's, fastest measured ~131us), stride-65
// Mperm (conflict-free prologue, R10-verified), and a VECTORIZED setup phase:
//  - all-float (S = I9 + small is well-conditioned; double only for Chebyshev)
//  - A staged duplicated in LDS (As2[9][128])
//  - P[m][i] = sum_d A[m][i+d]*binv[d] with 4-row shift-table binvS[i&3][68]
//    so every ds_read_b128 is 16B-aligned & conflict-free (34 reads/m vs 144
//    scalars in R10's setup)
//  - S and Q passes quad-vectorized (b128)
//  - Mfull ELIMINATED: each value is scattered directly into Mperm via the
//    inverse permutation k(i,j); binv[(i-j)&63] comes from shift-table bnS.
// R10's post-mortem attribution: fused setup cost ~18us (LDS scalar-read
// storms); this restructure targets ~7us.
// LDS pool 30704B -> >=5 blocks/CU by LDS (grid gives 4).
// ---------------------------------------------------------------------------
__global__ __launch_bounds__(256)
void admm_fused(const float* __restrict__ target, const float* __restrict__ A,
                const float* __restrict__ x0, float* __restrict__ out) {
  __shared__ __align__(16) char smem[30704];
  float* Mperm      = (float*)(smem);            // 64 rows, stride 65 -> 16640
  float (*rbuf)[64] = (float(*)[64])(smem + 16640);  // 1024 (aliases lamr)
  double* lamr      = (double*)(smem + 16640);       // 512, dead before rbuf
  float* binv       = (float*)(smem + 17664);        // 256
  float* binvN      = (float*)(smem + 17920);        // 256: binvN[d]=binv[(-d)&63]
  float (*binvS)[68]= (float(*)[68])(smem + 18176);  // 4x68 = 1088
  float (*bnS)[80]  = (float(*)[80])(smem + 19264);  // 4x80 = 1280
  float (*As2)[128] = (float(*)[128])(smem + 20544); // 4608 (dup rows)
  float (*P)[68]    = (float(*)[68])(smem + 25152);  // 2448
  float (*Q)[68]    = (float(*)[68])(smem + 27600);  // 2448
  float (*W)[18]    = (float(*)[18])(smem + 30048);  // 648

  const int tid = threadIdx.x;
  const int wid = tid >> 6;
  const int lane = tid & 63;
  const int s = blockIdx.x * 4 + wid;
  const double TWO_PI = 6.283185307179586476925286766559;

  // ---- pass 0: stage A duplicated into LDS ----
  for (int e = tid; e < 9 * 64; e += 256) {
    int m = e >> 6, k = e & 63;
    float a = A[e];
    As2[m][k] = a;
    As2[m][k + 64] = a;
  }

  // ---- pass 1: binv via Chebyshev (double, one wave) + binvN ----
  double cb = 0.0;
  if (tid < 64) {
    cb = cos(TWO_PI * (double)tid / 64.0);
    lamr[tid] = 1.0 / (9.0 - 4.0 * cb);
  }
  __syncthreads();
  if (tid < 64) {
    double cm1 = 1.0, c0 = cb;
    double acc = lamr[0] + cb * lamr[1];
#pragma unroll 16
    for (int m = 2; m < 64; ++m) {
      double c = 2.0 * cb * c0 - cm1;
      cm1 = c0;
      c0 = c;
      acc += c * lamr[m];
    }
    float b = (float)(acc / 64.0);
    binv[tid] = b;
    binvN[(64 - tid) & 63] = b;
  }
  __syncthreads();

  // ---- pass 2: shift tables ----
  for (int e = tid; e < 4 * 68; e += 256) {
    int sh = e / 68, d = e % 68;
    binvS[sh][d] = (d >= sh && d < 64 + sh) ? binv[d - sh] : 0.f;
  }
  for (int e = tid; e < 4 * 80; e += 256) {
    int sh = e / 80, d = e % 80;
    bnS[sh][d] = binvN[(d - sh) & 63];
  }
  __syncthreads();

  // ---- pass 3: P[m][i] = sum_d A[m][(i+d)&63] binv[d], aligned b128 ----
  {
    int w = wid, i = lane;
    int ia = i & ~3, sh = i & 3;
    for (int m = w; m < 9; m += 4) {
      const float4* ap = (const float4*)&As2[m][ia];   // 16B-aligned
      const float4* bp = (const float4*)&binvS[sh][0]; // 16B-aligned, 17 quads
      float acc = 0.f;
#pragma unroll
      for (int t = 0; t < 17; ++t) {
        float4 av = ap[t], bv = bp[t];
        acc = fmaf(av.x, bv.x, acc);
        acc = fmaf(av.y, bv.y, acc);
        acc = fmaf(av.z, bv.z, acc);
        acc = fmaf(av.w, bv.w, acc);
      }
      P[m][i] = acc;
    }
  }
  __syncthreads();

  // ---- pass 4: S = I9 + P A^T (81 threads, quad-vectorized) ----
  if (tid < 81) {
    int m = tid / 9, n = tid % 9;
    float acc = (m == n) ? 1.f : 0.f;
    const float4* pp = (const float4*)&P[m][0];
    const float4* aa = (const float4*)&As2[n][0];
#pragma unroll
    for (int q = 0; q < 16; ++q) {
      float4 pv = pp[q], av = aa[q];
      acc = fmaf(pv.x, av.x, acc);
      acc = fmaf(pv.y, av.y, acc);
      acc = fmaf(pv.z, av.z, acc);
      acc = fmaf(pv.w, av.w, acc);
    }
    W[m][n] = acc;
    W[m][n + 9] = (m == n) ? 1.f : 0.f;
  }
  __syncthreads();

  // ---- pass 5: parallel float Gauss-Jordan (S is near-identity, stable) ----
  {
    const int r9 = tid / 18, c9 = tid % 18;
    const bool act = (tid < 162);
    for (int k = 0; k < 9; ++k) {
      float pv = 1.f, f = 0.f, wkc = 0.f;
      if (act) {
        pv = W[k][k];
        f = W[r9][k];
        wkc = W[k][c9];
      }
      __syncthreads();
      if (act) {
        float nk = wkc / pv;
        W[r9][c9] = (r9 == k) ? nk : fmaf(-f, nk, W[r9][c9]);
      }
      __syncthreads();
    }
  }

  // ---- pass 6: Q = Sinv P (144 threads, quad-vectorized) ----
  if (tid < 144) {
    int m = tid >> 4, jq = tid & 15;
    float4 acc = {0.f, 0.f, 0.f, 0.f};
#pragma unroll
    for (int n = 0; n < 9; ++n) {
      float sv = W[m][n + 9];
      float4 pv = *(const float4*)&P[n][4 * jq];
      acc.x = fmaf(sv, pv.x, acc.x);
      acc.y = fmaf(sv, pv.y, acc.y);
      acc.z = fmaf(sv, pv.z, acc.z);
      acc.w = fmaf(sv, pv.w, acc.w);
    }
    *(float4*)&Q[m][4 * jq] = acc;
  }
  __syncthreads();

  // ---- probe DPP row_ror direction (register-only, per wave) ----
  int dpp1;
  asm volatile(
      "s_nop 4\n\t"
      "v_mov_b32_dpp %0, %1 row_ror:1 row_mask:0xf bank_mask:0xf\n\t"
      "s_nop 4"
      : "=v"(dpp1)
      : "v"(lane));
  const int dir = (__builtin_amdgcn_readfirstlane(dpp1) == 1) ? 1 : -1;

  // ---- pass 8: Mperm direct scatter (Mfull eliminated) ----
  // value(i,j) = binv[(i-j)&63] - sum_m P[m][i] Q[m][j], written to
  // Mperm[i][k(i,j)] where k is the inverse of the d=32 loop mapping:
  //   (j^i)&32        -> k = 32 + (j&31)                       (far half)
  //   else            -> t = (dir*((j&15)-(i&15)))&15
  //                      k = ((j^i)&16) ? 16+t : t             (DPP stages)
  {
    int i = tid >> 2, jb = tid & 3, j0 = jb * 16;
    int sh = i & 3;
    float pm[9];
#pragma unroll
    for (int m = 0; m < 9; ++m) pm[m] = P[m][i];

    float vq[16];
    {
      int b = (j0 - (i & ~3)) & 63;  // multiple of 4 -> aligned quads
      const float4* bq = (const float4*)&bnS[sh][b];
      float4 b0 = bq[0], b1 = bq[1], b2 = bq[2], b3 = bq[3];
      vq[0] = b0.x;  vq[1] = b0.y;  vq[2] = b0.z;  vq[3] = b0.w;
      vq[4] = b1.x;  vq[5] = b1.y;  vq[6] = b1.z;  vq[7] = b1.w;
      vq[8] = b2.x;  vq[9] = b2.y;  vq[10] = b2.z; vq[11] = b2.w;
      vq[12] = b3.x; vq[13] = b3.y; vq[14] = b3.z; vq[15] = b3.w;
    }
#pragma unroll
    for (int m = 0; m < 9; ++m) {
      float p = pm[m];
      const float4* qq = (const float4*)&Q[m][j0];
      float4 q0 = qq[0], q1 = qq[1], q2 = qq[2], q3 = qq[3];
      vq[0] = fmaf(-p, q0.x, vq[0]);   vq[1] = fmaf(-p, q0.y, vq[1]);
      vq[2] = fmaf(-p, q0.z, vq[2]);   vq[3] = fmaf(-p, q0.w, vq[3]);
      vq[4] = fmaf(-p, q1.x, vq[4]);   vq[5] = fmaf(-p, q1.y, vq[5]);
      vq[6] = fmaf(-p, q1.z, vq[6]);   vq[7] = fmaf(-p, q1.w, vq[7]);
      vq[8] = fmaf(-p, q2.x, vq[8]);   vq[9] = fmaf(-p, q2.y, vq[9]);
      vq[10] = fmaf(-p, q2.z, vq[10]); vq[11] = fmaf(-p, q2.w, vq[11]);
      vq[12] = fmaf(-p, q3.x, vq[12]); vq[13] = fmaf(-p, q3.y, vq[13]);
      vq[14] = fmaf(-p, q3.z, vq[14]); vq[15] = fmaf(-p, q3.w, vq[15]);
    }
#pragma unroll
    for (int e = 0; e < 16; ++e) {
      int j = j0 + e;
      int k;
      if ((j ^ i) & 32) {
        k = 32 + (j & 31);
      } else {
        int tt = (dir * ((j & 15) - (i & 15))) & 15;
        k = ((j ^ i) & 16) ? 16 + tt : tt;
      }
      Mperm[i * 65 + k] = vq[e];
    }
  }
  __syncthreads();

  // ---- ATb = (target_s @ A^T) @ A via 9 wave-reductions ----
  float t = target[s * 64 + lane];
  float atbv = 0.f;
#pragma unroll
  for (int m = 0; m < 9; ++m) {
    float a = A[m * 64 + lane];
    float p = t * a;
#pragma unroll
    for (int off = 32; off; off >>= 1) p += __shfl_xor(p, off, 64);
    atbv = fmaf(a, p, atbv);
  }

  unsigned int mprm = (unsigned int)(uintptr_t)(Mperm + lane * 65);
  unsigned int rb = (unsigned int)(uintptr_t)(&rbuf[wid][0]);
  unsigned int a_w = rb + lane * 4;
  unsigned int a_rf = rb + (((lane & 32) ^ 32) << 2);  // far 32-half base
  unsigned int a_nxt = ((lane + 1) & 63) * 4;          // bpermute lane+1
  float xin = x0[s * 64 + lane];
  float xout;
  int cnt_s;
  const int smask = 0x7fffffff;
  const float sthr = 5e-5f, sc02 = 0.2f, sc5 = 5.0f;

  asm volatile(
      "s_mov_b32 m0, -1\n\t"
      // --- M' row from LDS (stride 260B, conflict-free) into v64-v127 ---
      "ds_read_b128 v[64:67],   %[mprm]\n\t"
      "ds_read_b128 v[68:71],   %[mprm] offset:16\n\t"
      "ds_read_b128 v[72:75],   %[mprm] offset:32\n\t"
      "ds_read_b128 v[76:79],   %[mprm] offset:48\n\t"
      "ds_read_b128 v[80:83],   %[mprm] offset:64\n\t"
      "ds_read_b128 v[84:87],   %[mprm] offset:80\n\t"
      "ds_read_b128 v[88:91],   %[mprm] offset:96\n\t"
      "ds_read_b128 v[92:95],   %[mprm] offset:112\n\t"
      "ds_read_b128 v[96:99],   %[mprm] offset:128\n\t"
      "ds_read_b128 v[100:103], %[mprm] offset:144\n\t"
      "ds_read_b128 v[104:107], %[mprm] offset:160\n\t"
      "ds_read_b128 v[108:111], %[mprm] offset:176\n\t"
      "ds_read_b128 v[112:115], %[mprm] offset:192\n\t"
      "ds_read_b128 v[116:119], %[mprm] offset:208\n\t"
      "ds_read_b128 v[120:123], %[mprm] offset:224\n\t"
      "ds_read_b128 v[124:127], %[mprm] offset:240\n\t"
      // --- init: v32=x v33=eta v34=tau v35=Dx v36=atb ---
      "v_mov_b32 v32, %[xin]\n\t"
      "v_mov_b32 v36, %[atb]\n\t"
      "v_mov_b32 v33, 0\n\t"
      "v_mov_b32 v34, 0\n\t"
      "ds_bpermute_b32 v45, %[anx], v32\n\t"
      "s_waitcnt lgkmcnt(0)\n\t"
      "v_sub_f32 v35, v45, v32\n\t"
      "s_movk_i32 %[cnt], 200\n\t"
      "1:\n\t"
      // u = copysign(max(|0.5*eta+Dx|-thr,0), .) -> v42
      "v_fma_f32 v40, 0.5, v33, v35\n\t"
      "v_and_b32 v41, %[msk], v40\n\t"
      "v_subrev_f32 v41, %[thr], v41\n\t"
      "v_max_f32 v41, 0, v41\n\t"
      "v_bfi_b32 v42, %[msk], v41, v40\n\t"
      // w = max(0.2*tau + x, 0) -> v43
      "v_fma_f32 v43, %[c02], v34, v32\n\t"
      "v_max_f32 v43, 0, v43\n\t"
      // tv = 2u - eta -> v40 ; ts = tv[lane+1] via bpermute -> v45
      "v_fma_f32 v40, 2.0, v42, -v33\n\t"
      "ds_bpermute_b32 v45, %[anx], v40\n\t"
      // resid = 5w + atb - tau - tv + ts -> v44
      "v_fma_f32 v44, %[c5], v43, v36\n\t"
      "v_sub_f32 v44, v44, v34\n\t"
      "v_sub_f32 v44, v44, v40\n\t"
      "s_waitcnt lgkmcnt(0)\n\t"
      "v_add_f32 v44, v44, v45\n\t"
      // stage sources: write resid, xor16 swizzle, 8 far-half quad reads
      "ds_write_b32 %[aw], v44\n\t"
      "ds_swizzle_b32 v47, v44 offset:0x401F\n\t"
      "ds_read_b128 v[48:51], %[arf]\n\t"
      "ds_read_b128 v[52:55], %[arf] offset:16\n\t"
      "ds_read_b128 v[56:59], %[arf] offset:32\n\t"
      "ds_read_b128 v[60:63], %[arf] offset:48\n\t"
      "ds_read_b128 v[16:19], %[arf] offset:64\n\t"
      "ds_read_b128 v[20:23], %[arf] offset:80\n\t"
      "ds_read_b128 v[24:27], %[arf] offset:96\n\t"
      "ds_read_b128 v[28:31], %[arf] offset:112\n\t"
      // ---- stage 0: r=v44 (local), m=v64-79, DPP broadcasts ----
      "v_mul_f32 v37, v44, v64\n\t"
      DPL("v_mul_f32",  "v38", "v44", "v65", 1)
      DPL("v_mul_f32",  "v39", "v44", "v66", 2)
      DPL("v_mul_f32",  "v40", "v44", "v67", 3)
      DPL("v_fmac_f32", "v37", "v44", "v68", 4)
      DPL("v_fmac_f32", "v38", "v44", "v69", 5)
      DPL("v_fmac_f32", "v39", "v44", "v70", 6)
      DPL("v_fmac_f32", "v40", "v44", "v71", 7)
      DPL("v_fmac_f32", "v37", "v44", "v72", 8)
      DPL("v_fmac_f32", "v38", "v44", "v73", 9)
      DPL("v_fmac_f32", "v39", "v44", "v74", 10)
      DPL("v_fmac_f32", "v40", "v44", "v75", 11)
      DPL("v_fmac_f32", "v37", "v44", "v76", 12)
      DPL("v_fmac_f32", "v38", "v44", "v77", 13)
      DPL("v_fmac_f32", "v39", "v44", "v78", 14)
      DPL("v_fmac_f32", "v40", "v44", "v79", 15)
      // write+swizzle retired (10 outstanding -> 8): v47 ready
      "s_waitcnt lgkmcnt(8)\n\t"
      "s_nop 1\n\t"
      // ---- stage 1: r=v47 (xor16), m=v80-95 ----
      "v_fmac_f32 v37, v47, v80\n\t"
      DPL("v_fmac_f32", "v38", "v47", "v81", 1)
      DPL("v_fmac_f32", "v39", "v47", "v82", 2)
      DPL("v_fmac_f32", "v40", "v47", "v83", 3)
      DPL("v_fmac_f32", "v37", "v47", "v84", 4)
      DPL("v_fmac_f32", "v38", "v47", "v85", 5)
      DPL("v_fmac_f32", "v39", "v47", "v86", 6)
      DPL("v_fmac_f32", "v40", "v47", "v87", 7)
      DPL("v_fmac_f32", "v37", "v47", "v88", 8)
      DPL("v_fmac_f32", "v38", "v47", "v89", 9)
      DPL("v_fmac_f32", "v39", "v47", "v90", 10)
      DPL("v_fmac_f32", "v40", "v47", "v91", 11)
      DPL("v_fmac_f32", "v37", "v47", "v92", 12)
      DPL("v_fmac_f32", "v38", "v47", "v93", 13)
      DPL("v_fmac_f32", "v39", "v47", "v94", 14)
      DPL("v_fmac_f32", "v40", "v47", "v95", 15)
      // first 4 quads ready
      "s_waitcnt lgkmcnt(4)\n\t"
      // ---- stage 2: far[0..15] = v48-63, m=v96-111, plain 2-cyc fmacs ----
      "v_fmac_f32 v37, v48, v96\n\t"
      "v_fmac_f32 v38, v49, v97\n\t"
      "v_fmac_f32 v39, v50, v98\n\t"
      "v_fmac_f32 v40, v51, v99\n\t"
      "v_fmac_f32 v37, v52, v100\n\t"
      "v_fmac_f32 v38, v53, v101\n\t"
      "v_fmac_f32 v39, v54, v102\n\t"
      "v_fmac_f32 v40, v55, v103\n\t"
      "v_fmac_f32 v37, v56, v104\n\t"
      "v_fmac_f32 v38, v57, v105\n\t"
      "v_fmac_f32 v39, v58, v106\n\t"
      "v_fmac_f32 v40, v59, v107\n\t"
      "v_fmac_f32 v37, v60, v108\n\t"
      "v_fmac_f32 v38, v61, v109\n\t"
      "v_fmac_f32 v39, v62, v110\n\t"
      "v_fmac_f32 v40, v63, v111\n\t"
      "s_waitcnt lgkmcnt(0)\n\t"
      // ---- stage 3: far[16..31] = v16-31, m=v112-127 ----
      "v_fmac_f32 v37, v16, v112\n\t"
      "v_fmac_f32 v38, v17, v113\n\t"
      "v_fmac_f32 v39, v18, v114\n\t"
      "v_fmac_f32 v40, v19, v115\n\t"
      "v_fmac_f32 v37, v20, v116\n\t"
      "v_fmac_f32 v38, v21, v117\n\t"
      "v_fmac_f32 v39, v22, v118\n\t"
      "v_fmac_f32 v40, v23, v119\n\t"
      "v_fmac_f32 v37, v24, v120\n\t"
      "v_fmac_f32 v38, v25, v121\n\t"
      "v_fmac_f32 v39, v26, v122\n\t"
      "v_fmac_f32 v40, v27, v123\n\t"
      "v_fmac_f32 v37, v28, v124\n\t"
      "v_fmac_f32 v38, v29, v125\n\t"
      "v_fmac_f32 v39, v30, v126\n\t"
      "v_fmac_f32 v40, v31, v127\n\t"
      // combine -> x_new in v32
      "v_add_f32 v37, v37, v38\n\t"
      "v_add_f32 v39, v39, v40\n\t"
      "v_add_f32 v32, v37, v39\n\t"
      // Dx = x[lane+1] - x ; duals (tau update overlaps bpermute)
      "ds_bpermute_b32 v45, %[anx], v32\n\t"
      "v_sub_f32 v41, v32, v43\n\t"
      "v_fma_f32 v34, %[c5], v41, v34\n\t"
      "s_waitcnt lgkmcnt(0)\n\t"
      "v_sub_f32 v35, v45, v32\n\t"
      "v_sub_f32 v41, v35, v42\n\t"
      "v_fma_f32 v33, 2.0, v41, v33\n\t"
      "s_sub_u32 %[cnt], %[cnt], 1\n\t"
      "s_cmp_lg_u32 %[cnt], 0\n\t"
      "s_cbranch_scc1 1b\n\t"
      "v_mov_b32 %[xout], v32\n\t"
      : [xout] "=v"(xout), [cnt] "=&s"(cnt_s)
      : [mprm] "v"(mprm), [aw] "v"(a_w), [arf] "v"(a_rf), [anx] "v"(a_nxt),
        [xin] "v"(xin), [atb] "v"(atbv),
        [msk] "s"(smask), [thr] "s"(sthr), [c02] "s"(sc02), [c5] "s"(sc5)
      : "memory", "scc",
        "v16","v17","v18","v19","v20","v21","v22","v23","v24","v25","v26","v27",
        "v28","v29","v30","v31",
        "v32","v33","v34","v35","v36","v37","v38","v39","v40","v41","v42","v43",
        "v44","v45","v46","v47","v48","v49","v50","v51","v52","v53","v54","v55",
        "v56","v57","v58","v59","v60","v61","v62","v63","v64","v65","v66","v67",
        "v68","v69","v70","v71","v72","v73","v74","v75","v76","v77","v78","v79",
        "v80","v81","v82","v83","v84","v85","v86","v87","v88","v89","v90","v91",
        "v92","v93","v94","v95","v96","v97","v98","v99","v100","v101","v102",
        "v103","v104","v105","v106","v107","v108","v109","v110","v111","v112",
        "v113","v114","v115","v116","v117","v118","v119","v120","v121","v122",
        "v123","v124","v125","v126","v127");

  out[s * 64 + lane] = xout;
}

extern "C" void kernel_launch(void* const* d_in, const int* in_sizes, int n_in,
                              void* d_out, int out_size, void* d_ws, size_t ws_size,
                              hipStream_t stream) {
  const float* target = (const float*)d_in[0];  // (4096, 64)
  const float* A = (const float*)d_in[1];       // (9, 64)
  const float* x0 = (const float*)d_in[2];      // (4096, 64)
  float* out = (float*)d_out;                   // (4096, 64)

  admm_fused<<<NSAMP / 4, 256, 0, stream>>>(target, A, x0, out);
}